// Round 8
// baseline (485.123 us; speedup 1.0000x reference)
//
#include <hip/hip_runtime.h>
#include <hip/hip_bf16.h>
#include <math.h>

#define BATCH 8
#define HH 1024
#define WW 1024

__device__ __forceinline__ int reflect1024(int i) {
    i = i < 0 ? -i : i;
    return i > 1023 ? 2046 - i : i;
}

// ---------------------------------------------------------------------------
// conv0: concat(nearest_resize(lqs,256)[3], evs[15]) -> (8,18,3,3) s2 p1
// + bias + relu -> [B,8,128,128]. 4 output px along x per thread.
// ---------------------------------------------------------------------------
__global__ __launch_bounds__(256) void conv0_k(const float* __restrict__ lqs,
                                               const float* __restrict__ evs,
                                               const float* __restrict__ w,
                                               const float* __restrict__ bias,
                                               float* __restrict__ out) {
    int idx = blockIdx.x * 256 + threadIdx.x;  // B * 4096
    int q = idx & 4095;
    int b = idx >> 12;
    int qx = q & 31, oy = q >> 5;
    int iy0 = oy * 2 - 1;

    float acc[4][8];
#pragma unroll
    for (int j = 0; j < 4; ++j)
#pragma unroll
        for (int o = 0; o < 8; ++o) acc[j][o] = bias[o];

#pragma unroll
    for (int ic = 0; ic < 3; ++ic) {
        const float* ipc = lqs + (size_t)(b * 3 + ic) * HH * WW;
#pragma unroll
        for (int ky = 0; ky < 3; ++ky) {
            int iy = iy0 + ky;
            if (iy < 0) continue;
            const float* row = ipc + (size_t)iy * 4 * WW;
            float xr[9];
#pragma unroll
            for (int i = 0; i < 9; ++i) {
                int ix = 8 * qx - 1 + i;
                xr[i] = (ix >= 0) ? row[ix * 4] : 0.0f;
            }
#pragma unroll
            for (int o = 0; o < 8; ++o) {
                const float* wp = w + (o * 18 + ic) * 9 + ky * 3;
#pragma unroll
                for (int j = 0; j < 4; ++j)
#pragma unroll
                    for (int kx = 0; kx < 3; ++kx)
                        acc[j][o] = fmaf(wp[kx], xr[2 * j + kx], acc[j][o]);
            }
        }
    }
    for (int ic = 0; ic < 15; ++ic) {
        const float* ipc = evs + (size_t)(b * 15 + ic) * 65536;
#pragma unroll
        for (int ky = 0; ky < 3; ++ky) {
            int iy = iy0 + ky;
            if (iy < 0) continue;
            const float* row = ipc + iy * 256;
            const float4* r4 = (const float4*)row;
            float4 A = r4[2 * qx];
            float4 Bv = r4[2 * qx + 1];
            float m = (qx > 0) ? row[8 * qx - 1] : 0.0f;
            float xr[9] = {m, A.x, A.y, A.z, A.w, Bv.x, Bv.y, Bv.z, Bv.w};
#pragma unroll
            for (int o = 0; o < 8; ++o) {
                const float* wp = w + (o * 18 + ic + 3) * 9 + ky * 3;
#pragma unroll
                for (int j = 0; j < 4; ++j)
#pragma unroll
                    for (int kx = 0; kx < 3; ++kx)
                        acc[j][o] = fmaf(wp[kx], xr[2 * j + kx], acc[j][o]);
            }
        }
    }
#pragma unroll
    for (int o = 0; o < 8; ++o) {
        float4 v = make_float4(fmaxf(acc[0][o], 0.0f), fmaxf(acc[1][o], 0.0f),
                               fmaxf(acc[2][o], 0.0f), fmaxf(acc[3][o], 0.0f));
        *(float4*)(out + ((size_t)(b * 8 + o) << 14) + oy * 128 + qx * 4) = v;
    }
}

// ---------------------------------------------------------------------------
// generic 3x3 conv, pad=1, OCT output channels per thread. OCT chosen low
// (1-4) so every launch has >=128 blocks: parallelism beats per-dispatch
// serial chains on this latency-bound tail (R6/R7 lesson).
// ---------------------------------------------------------------------------
template <int IC, int OC, int OCT, int IH, int IW, int STRIDE, bool RELU, bool HASB>
__global__ __launch_bounds__(256) void convN_k(const float* __restrict__ in,
                                               const float* __restrict__ w,
                                               const float* __restrict__ bias,
                                               float* __restrict__ out) {
    constexpr int OH = (IH + 2 - 3) / STRIDE + 1;
    constexpr int OW = (IW + 2 - 3) / STRIDE + 1;
    constexpr int POS = OH * OW;
    constexpr int G = OC / OCT;
    int idx = blockIdx.x * 256 + threadIdx.x;
    if (idx >= BATCH * G * POS) return;
    int px = idx % POS;
    int g = (idx / POS) % G;
    int b = idx / (POS * G);
    int ox = px % OW, oy = px / OW;
    int iy0 = oy * STRIDE - 1, ix0 = ox * STRIDE - 1;

    float acc[OCT];
#pragma unroll
    for (int o = 0; o < OCT; ++o) acc[o] = HASB ? bias[g * OCT + o] : 0.0f;

    const float* ip = in + (size_t)b * IC * IH * IW;
    for (int ic = 0; ic < IC; ++ic) {
        const float* ipc = ip + ic * IH * IW;
        float x[9];
#pragma unroll
        for (int ky = 0; ky < 3; ++ky) {
            int iy = iy0 + ky;
#pragma unroll
            for (int kx = 0; kx < 3; ++kx) {
                int ix = ix0 + kx;
                bool ok = (iy >= 0) && (iy < IH) && (ix >= 0) && (ix < IW);
                x[ky * 3 + kx] = ok ? ipc[iy * IW + ix] : 0.0f;
            }
        }
#pragma unroll
        for (int o = 0; o < OCT; ++o) {
            const float* wp = w + ((g * OCT + o) * IC + ic) * 9;
#pragma unroll
            for (int k = 0; k < 9; ++k) acc[o] = fmaf(wp[k], x[k], acc[o]);
        }
    }
#pragma unroll
    for (int o = 0; o < OCT; ++o) {
        float v = acc[o];
        if (RELU) v = fmaxf(v, 0.0f);
        out[(size_t)(b * OC + g * OCT + o) * POS + px] = v;
    }
}

// ---------------------------------------------------------------------------
// split-K 3x3 conv (only used for cw1, whose reduce folds into fc1 free).
// ---------------------------------------------------------------------------
template <int IC, int OC, int OCT, int IH, int IW, int STRIDE, int SPLIT>
__global__ __launch_bounds__(256) void convS_k(const float* __restrict__ in,
                                               const float* __restrict__ w,
                                               float* __restrict__ part) {
    constexpr int OH = (IH + 2 - 3) / STRIDE + 1;
    constexpr int OW = (IW + 2 - 3) / STRIDE + 1;
    constexpr int POS = OH * OW;
    constexpr int G = OC / OCT;
    constexpr int TOT = BATCH * G * POS;
    constexpr int ICS = IC / SPLIT;
    constexpr int N = BATCH * OC * POS;
    int idx = blockIdx.x * 256 + threadIdx.x;
    if (idx >= TOT * SPLIT) return;
    int s = idx / TOT, r = idx % TOT;
    int px = r % POS;
    int g = (r / POS) % G;
    int b = r / (POS * G);
    int ox = px % OW, oy = px / OW;
    int iy0 = oy * STRIDE - 1, ix0 = ox * STRIDE - 1;

    float acc[OCT];
#pragma unroll
    for (int o = 0; o < OCT; ++o) acc[o] = 0.0f;

    const float* ip = in + (size_t)b * IC * IH * IW;
    for (int ic = s * ICS; ic < (s + 1) * ICS; ++ic) {
        const float* ipc = ip + ic * IH * IW;
        float x[9];
#pragma unroll
        for (int ky = 0; ky < 3; ++ky) {
            int iy = iy0 + ky;
#pragma unroll
            for (int kx = 0; kx < 3; ++kx) {
                int ix = ix0 + kx;
                bool ok = (iy >= 0) && (iy < IH) && (ix >= 0) && (ix < IW);
                x[ky * 3 + kx] = ok ? ipc[iy * IW + ix] : 0.0f;
            }
        }
#pragma unroll
        for (int o = 0; o < OCT; ++o) {
            const float* wp = w + ((g * OCT + o) * IC + ic) * 9;
#pragma unroll
            for (int k = 0; k < 9; ++k) acc[o] = fmaf(wp[k], x[k], acc[o]);
        }
    }
#pragma unroll
    for (int o = 0; o < OCT; ++o)
        part[(size_t)s * N + (size_t)(b * OC + g * OCT + o) * POS + px] = acc[o];
}

// ---------------------------------------------------------------------------
// fc1: folds cw1's split-16 reduce (+cb1+relu) into xin, then
// h1[b,r] = relu(fw1[r,:] . xin + fb1[r]).  512 blocks, 1 row per wave.
// ---------------------------------------------------------------------------
__global__ __launch_bounds__(256) void fc1_k(const float* __restrict__ part_cw1,
                                             const float* __restrict__ cb1,
                                             const float* __restrict__ fw1,
                                             const float* __restrict__ fb1,
                                             float* __restrict__ h1) {
    __shared__ float xin[1024];
    int t = threadIdx.x;
    int b = blockIdx.x >> 6;
    int rgrp = blockIdx.x & 63;
    int wave = t >> 6, lane = t & 63;

    for (int i = t; i < 1024; i += 256) {
        float v = cb1[i >> 4];        // xg1 flat idx i = oc*16+px, POS=16
#pragma unroll
        for (int s = 0; s < 16; ++s) v += part_cw1[s * 8192 + b * 1024 + i];
        xin[i] = fmaxf(v, 0.0f);
    }
    __syncthreads();

    int r = (rgrp << 2) | wave;       // 0..255
    const float4* w4 = (const float4*)(fw1 + r * 1024);
    const float4* x4 = (const float4*)xin;
    float acc = 0.0f;
#pragma unroll
    for (int jj = 0; jj < 4; ++jj) {
        float4 wv = w4[lane + 64 * jj];
        float4 xv = x4[lane + 64 * jj];
        acc = fmaf(wv.x, xv.x, acc);
        acc = fmaf(wv.y, xv.y, acc);
        acc = fmaf(wv.z, xv.z, acc);
        acc = fmaf(wv.w, xv.w, acc);
    }
#pragma unroll
    for (int m = 32; m; m >>= 1) acc += __shfl_xor(acc, m, 64);
    if (lane == 0) h1[b * 256 + r] = fmaxf(acc + fb1[r], 0.0f);
}

// ---------------------------------------------------------------------------
// fc2+fc3+fuse merged: one block per batch, staged through LDS.
//   h2 = relu(fw2 @ h1 + fb2)          (4 waves x 32 rows, lane-split K)
//   xg = fw3 @ h2 + fb3                (4 waves x 16 rows)
//   bg[b,d,px] = fub[d] + sum_c fuw[d,c]*relu(xg[c]+xl2[b,c,px])
// ---------------------------------------------------------------------------
__global__ __launch_bounds__(256) void fc23fuse_k(const float* __restrict__ h1,
                                                  const float* __restrict__ fw2,
                                                  const float* __restrict__ fb2,
                                                  const float* __restrict__ fw3,
                                                  const float* __restrict__ fb3,
                                                  const float* __restrict__ xl2,
                                                  const float* __restrict__ fuw,
                                                  const float* __restrict__ fub,
                                                  float* __restrict__ bg) {
    __shared__ float h2[128];
    __shared__ float xg[64];
    int b = blockIdx.x, t = threadIdx.x;
    int wave = t >> 6, lane = t & 63;

    float4 xv1 = ((const float4*)(h1 + b * 256))[lane];
#pragma unroll 4
    for (int i = 0; i < 32; ++i) {
        int r = wave * 32 + i;
        float4 wv = ((const float4*)(fw2 + r * 256))[lane];
        float acc = fmaf(wv.x, xv1.x, fmaf(wv.y, xv1.y, fmaf(wv.z, xv1.z, wv.w * xv1.w)));
#pragma unroll
        for (int m = 32; m; m >>= 1) acc += __shfl_xor(acc, m, 64);
        if (lane == 0) h2[r] = fmaxf(acc + fb2[r], 0.0f);
    }
    __syncthreads();

    float2 xv2 = ((const float2*)h2)[lane];
#pragma unroll 4
    for (int i = 0; i < 16; ++i) {
        int r = wave * 16 + i;
        float2 wv = ((const float2*)(fw3 + r * 128))[lane];
        float acc = fmaf(wv.x, xv2.x, wv.y * xv2.y);
#pragma unroll
        for (int m = 32; m; m >>= 1) acc += __shfl_xor(acc, m, 64);
        if (lane == 0) xg[r] = acc + fb3[r];
    }
    __syncthreads();

    int px = t;
    float acc[8];
#pragma unroll
    for (int d = 0; d < 8; ++d) acc[d] = fub[d];
    for (int c = 0; c < 64; ++c) {
        float f = fmaxf(xg[c] + xl2[(b * 64 + c) * 256 + px], 0.0f);
#pragma unroll
        for (int d = 0; d < 8; ++d) acc[d] = fmaf(fuw[d * 64 + c], f, acc[d]);
    }
#pragma unroll
    for (int d = 0; d < 8; ++d) bg[(b * 8 + d) * 256 + px] = acc[d];
}

// ---------------------------------------------------------------------------
// guide+slice (unchanged): vertical-first separable blur, sliding register
// windows, per-px guide MLP + trilinear grid slice.
// ---------------------------------------------------------------------------
__global__ __launch_bounds__(256) void guide_slice_k(const float* __restrict__ lqs,
                                                     const float* __restrict__ bgp,
                                                     const float* __restrict__ gw1,
                                                     const float* __restrict__ gb1,
                                                     const float* __restrict__ gw2,
                                                     const float* __restrict__ gb2,
                                                     float* __restrict__ out) {
    constexpr int TW = 64, TH = 32;
    __shared__ float sBH[3][TH][81];
    __shared__ float sBG[2048];
    __shared__ float sW1[48], sB1[16], sW2[16], sB2v[1];

    int t = threadIdx.x;
    int bx = blockIdx.x & 15;
    int by = (blockIdx.x >> 4) & 31;
    int b = blockIdx.x >> 9;
    int x0 = bx * TW, y0 = by * TH;

    float gv[17];
    {
        float gs = 0.0f;
#pragma unroll
        for (int i = 0; i < 17; ++i) {
            float d = (float)i - 8.0f;
            gv[i] = expf(-(d * d) * 0.125f);
            gs += gv[i];
        }
        float inv = 1.0f / gs;
#pragma unroll
        for (int i = 0; i < 17; ++i) gv[i] *= inv;
    }

    for (int i = t; i < 2048; i += 256) sBG[i] = bgp[b * 2048 + i];
    if (t < 48) sW1[t] = gw1[t];
    if (t < 16) { sB1[t] = gb1[t]; sW2[t] = gw2[t]; }
    if (t == 0) sB2v[0] = gb2[0];

    if (t < 240) {
        int c = t / 80, xo = t % 80;
        int gx = reflect1024(x0 + xo - 8);
        const float* colp = lqs + (size_t)(b * 3 + c) * HH * WW + gx;
        float win[17];
#pragma unroll
        for (int i = 0; i < 16; ++i)
            win[i] = colp[(size_t)reflect1024(y0 - 8 + i) * WW];
#pragma unroll
        for (int j = 0; j < TH; ++j) {
            win[(16 + j) % 17] = colp[(size_t)reflect1024(y0 + 8 + j) * WW];
            float acc = 0.0f;
#pragma unroll
            for (int i = 0; i < 17; ++i) acc = fmaf(gv[i], win[(j + i) % 17], acc);
            sBH[c][j][xo] = acc;
        }
    }
    __syncthreads();

    int yy = t >> 3, xs = (t & 7) * 8;
    int Y = y0 + yy;
    float fy = fminf(fmaxf((Y + 0.5f) * (1.0f / 64.0f) + 3.5f, 0.0f), 15.0f);
    float yf = floorf(fy);
    int yi = (int)yf;
    float ay = fy - yf;
    int yi1 = min(yi + 1, 15);

    float bcv[3][8];
#pragma unroll
    for (int c = 0; c < 3; ++c) {
        float win[17];
#pragma unroll
        for (int i = 0; i < 16; ++i) win[i] = sBH[c][yy][xs + i];
#pragma unroll
        for (int j = 0; j < 8; ++j) {
            win[(16 + j) % 17] = sBH[c][yy][xs + 16 + j];
            float acc = 0.0f;
#pragma unroll
            for (int i = 0; i < 17; ++i) acc = fmaf(gv[i], win[(j + i) % 17], acc);
            bcv[c][j] = acc;
        }
    }

    float val[8];
#pragma unroll
    for (int j = 0; j < 8; ++j) {
        float b0 = bcv[0][j], b1 = bcv[1][j], b2 = bcv[2][j];
        float s = sB2v[0];
#pragma unroll
        for (int c = 0; c < 16; ++c) {
            float g1 = fmaf(sW1[c * 3 + 0], b0,
                       fmaf(sW1[c * 3 + 1], b1,
                       fmaf(sW1[c * 3 + 2], b2, sB1[c])));
            s = fmaf(sW2[c], fmaxf(g1, 0.0f), s);
        }
        float sig = 1.0f / (1.0f + expf(-s));
        float guide = sig * 2.0f - 0.5f;

        int X = x0 + xs + j;
        float fx = fminf(fmaxf((X + 0.5f) * (1.0f / 64.0f) + 3.5f, 0.0f), 15.0f);
        float fz = fminf(fmaxf(fmaf(guide, 4.0f, 3.5f), 0.0f), 7.0f);
        float xf = floorf(fx), zf = floorf(fz);
        int xi = (int)xf, zi = (int)zf;
        float ax = fx - xf, az = fz - zf;
        int xi1 = min(xi + 1, 15), zi1 = min(zi + 1, 7);

        const float* g0 = sBG + zi * 256;
        const float* g1p = sBG + zi1 * 256;
        int i00 = yi * 16 + xi, i01 = yi * 16 + xi1;
        int i10 = yi1 * 16 + xi, i11 = yi1 * 16 + xi1;
        float c00 = g0[i00] + az * (g1p[i00] - g0[i00]);
        float c01 = g0[i01] + az * (g1p[i01] - g0[i01]);
        float c10 = g0[i10] + az * (g1p[i10] - g0[i10]);
        float c11 = g0[i11] + az * (g1p[i11] - g0[i11]);
        float c0 = c00 + ay * (c10 - c00);
        float c1 = c01 + ay * (c11 - c01);
        val[j] = c0 + ax * (c1 - c0);
    }
    float4* op = (float4*)(out + (size_t)b * HH * WW + (size_t)Y * WW + x0 + xs);
    op[0] = make_float4(val[0], val[1], val[2], val[3]);
    op[1] = make_float4(val[4], val[5], val[6], val[7]);
}

// ---------------------------------------------------------------------------
extern "C" void kernel_launch(void* const* d_in, const int* in_sizes, int n_in,
                              void* d_out, int out_size, void* d_ws, size_t ws_size,
                              hipStream_t stream) {
    const float* lqs = (const float*)d_in[0];
    const float* evs = (const float*)d_in[1];
    const float* gw1 = (const float*)d_in[2];
    const float* gb1 = (const float*)d_in[3];
    const float* gw2 = (const float*)d_in[4];
    const float* gb2 = (const float*)d_in[5];
    const float* sw0 = (const float*)d_in[6];
    const float* sb0 = (const float*)d_in[7];
    const float* sw1 = (const float*)d_in[8];
    const float* sb1 = (const float*)d_in[9];
    const float* sw2 = (const float*)d_in[10];
    const float* sb2 = (const float*)d_in[11];
    const float* sw3 = (const float*)d_in[12];
    const float* sb3 = (const float*)d_in[13];
    const float* cw0 = (const float*)d_in[14];
    const float* cb0 = (const float*)d_in[15];
    const float* cw1 = (const float*)d_in[16];
    const float* cb1 = (const float*)d_in[17];
    const float* fw1 = (const float*)d_in[18];
    const float* fb1 = (const float*)d_in[19];
    const float* fw2 = (const float*)d_in[20];
    const float* fb2 = (const float*)d_in[21];
    const float* fw3 = (const float*)d_in[22];
    const float* fb3 = (const float*)d_in[23];
    const float* lw1 = (const float*)d_in[24];
    const float* lb1 = (const float*)d_in[25];
    const float* lw2 = (const float*)d_in[26];
    const float* fuw = (const float*)d_in[27];
    const float* fub = (const float*)d_in[28];
    float* out = (float*)d_out;

    float* ws = (float*)d_ws;
    float* o0 = ws;                  // [8,8,128,128]   1048576
    float* o1 = o0 + 1048576;        // [8,16,64,64]     524288
    float* o2 = o1 + 524288;         // [8,32,32,32]     262144
    float* o3 = o2 + 262144;         // [8,64,16,16]     131072
    float* xl1 = o3 + 131072;        // [8,64,16,16]     131072
    float* xl2 = xl1 + 131072;       // [8,64,16,16]     131072
    float* xg0 = xl2 + 131072;       // [8,64,8,8]        32768
    float* h1 = xg0 + 32768;         // [8,256]            2048
    float* bg = h1 + 2048;           // [8,8,16,16]       16384
    float* part_cw1 = bg + 16384;    // [16][8,64,4,4]   131072
    // total ~2.42M floats = 9.7 MB

    // lowres stream — 8 direct conv dispatches (no split-K reduces)
    conv0_k<<<128, 256, 0, stream>>>(lqs, evs, sw0, sb0, o0);
    convN_k<8, 16, 4, 128, 128, 2, true, true><<<512, 256, 0, stream>>>(o0, sw1, sb1, o1);
    convN_k<16, 32, 2, 64, 64, 2, true, true><<<512, 256, 0, stream>>>(o1, sw2, sb2, o2);
    convN_k<32, 64, 1, 32, 32, 2, true, true><<<512, 256, 0, stream>>>(o2, sw3, sb3, o3);
    // local path
    convN_k<64, 64, 1, 16, 16, 1, true, true><<<512, 256, 0, stream>>>(o3, lw1, lb1, xl1);
    convN_k<64, 64, 1, 16, 16, 1, false, false><<<512, 256, 0, stream>>>(xl1, lw2, nullptr, xl2);
    // global path
    convN_k<64, 64, 1, 16, 16, 2, true, true><<<128, 256, 0, stream>>>(o3, cw0, cb0, xg0);
    convS_k<64, 64, 4, 8, 8, 2, 16><<<128, 256, 0, stream>>>(xg0, cw1, part_cw1);
    // (cw1 reduce folded into fc1_k)
    fc1_k<<<512, 256, 0, stream>>>(part_cw1, cb1, fw1, fb1, h1);
    fc23fuse_k<<<8, 256, 0, stream>>>(h1, fw2, fb2, fw3, fb3, xl2, fuw, fub, bg);
    // highres guide + slice
    guide_slice_k<<<BATCH * 32 * 16, 256, 0, stream>>>(lqs, bg, gw1, gb1, gw2, gb2, out);
}

// Round 9
// 431.178 us; speedup vs baseline: 1.1251x; 1.1251x over previous
//
#include <hip/hip_runtime.h>
#include <hip/hip_bf16.h>
#include <math.h>

#define BATCH 8
#define HH 1024
#define WW 1024

__device__ __forceinline__ int reflect1024(int i) {
    i = i < 0 ? -i : i;
    return i > 1023 ? 2046 - i : i;
}

// ---------------------------------------------------------------------------
// conv0: concat(nearest_resize(lqs,256)[3], evs[15]) -> (8,18,3,3) s2 p1
// + bias + relu -> [B,8,128,128]. 4 output px along x per thread.
// ---------------------------------------------------------------------------
__global__ __launch_bounds__(256) void conv0_k(const float* __restrict__ lqs,
                                               const float* __restrict__ evs,
                                               const float* __restrict__ w,
                                               const float* __restrict__ bias,
                                               float* __restrict__ out) {
    int idx = blockIdx.x * 256 + threadIdx.x;  // B * 4096
    int q = idx & 4095;
    int b = idx >> 12;
    int qx = q & 31, oy = q >> 5;
    int iy0 = oy * 2 - 1;

    float acc[4][8];
#pragma unroll
    for (int j = 0; j < 4; ++j)
#pragma unroll
        for (int o = 0; o < 8; ++o) acc[j][o] = bias[o];

#pragma unroll
    for (int ic = 0; ic < 3; ++ic) {
        const float* ipc = lqs + (size_t)(b * 3 + ic) * HH * WW;
#pragma unroll
        for (int ky = 0; ky < 3; ++ky) {
            int iy = iy0 + ky;
            if (iy < 0) continue;
            const float* row = ipc + (size_t)iy * 4 * WW;
            float xr[9];
#pragma unroll
            for (int i = 0; i < 9; ++i) {
                int ix = 8 * qx - 1 + i;
                xr[i] = (ix >= 0) ? row[ix * 4] : 0.0f;
            }
#pragma unroll
            for (int o = 0; o < 8; ++o) {
                const float* wp = w + (o * 18 + ic) * 9 + ky * 3;
#pragma unroll
                for (int j = 0; j < 4; ++j)
#pragma unroll
                    for (int kx = 0; kx < 3; ++kx)
                        acc[j][o] = fmaf(wp[kx], xr[2 * j + kx], acc[j][o]);
            }
        }
    }
    for (int ic = 0; ic < 15; ++ic) {
        const float* ipc = evs + (size_t)(b * 15 + ic) * 65536;
#pragma unroll
        for (int ky = 0; ky < 3; ++ky) {
            int iy = iy0 + ky;
            if (iy < 0) continue;
            const float* row = ipc + iy * 256;
            const float4* r4 = (const float4*)row;
            float4 A = r4[2 * qx];
            float4 Bv = r4[2 * qx + 1];
            float m = (qx > 0) ? row[8 * qx - 1] : 0.0f;
            float xr[9] = {m, A.x, A.y, A.z, A.w, Bv.x, Bv.y, Bv.z, Bv.w};
#pragma unroll
            for (int o = 0; o < 8; ++o) {
                const float* wp = w + (o * 18 + ic + 3) * 9 + ky * 3;
#pragma unroll
                for (int j = 0; j < 4; ++j)
#pragma unroll
                    for (int kx = 0; kx < 3; ++kx)
                        acc[j][o] = fmaf(wp[kx], xr[2 * j + kx], acc[j][o]);
            }
        }
    }
#pragma unroll
    for (int o = 0; o < 8; ++o) {
        float4 v = make_float4(fmaxf(acc[0][o], 0.0f), fmaxf(acc[1][o], 0.0f),
                               fmaxf(acc[2][o], 0.0f), fmaxf(acc[3][o], 0.0f));
        *(float4*)(out + ((size_t)(b * 8 + o) << 14) + oy * 128 + qx * 4) = v;
    }
}

// ---------------------------------------------------------------------------
// generic 3x3 conv (unsplit), pad=1, OCT output channels per thread.
// R8 lesson: keep OCT >= 8 for input-reuse (1:8 load:FMA); use split-K for
// parallelism, NOT lower OCT.
// ---------------------------------------------------------------------------
template <int IC, int OC, int OCT, int IH, int IW, int STRIDE, bool RELU, bool HASB>
__global__ __launch_bounds__(256) void convN_k(const float* __restrict__ in,
                                               const float* __restrict__ w,
                                               const float* __restrict__ bias,
                                               float* __restrict__ out) {
    constexpr int OH = (IH + 2 - 3) / STRIDE + 1;
    constexpr int OW = (IW + 2 - 3) / STRIDE + 1;
    constexpr int POS = OH * OW;
    constexpr int G = OC / OCT;
    int idx = blockIdx.x * 256 + threadIdx.x;
    if (idx >= BATCH * G * POS) return;
    int px = idx % POS;
    int g = (idx / POS) % G;
    int b = idx / (POS * G);
    int ox = px % OW, oy = px / OW;
    int iy0 = oy * STRIDE - 1, ix0 = ox * STRIDE - 1;

    float acc[OCT];
#pragma unroll
    for (int o = 0; o < OCT; ++o) acc[o] = HASB ? bias[g * OCT + o] : 0.0f;

    const float* ip = in + (size_t)b * IC * IH * IW;
    for (int ic = 0; ic < IC; ++ic) {
        const float* ipc = ip + ic * IH * IW;
        float x[9];
#pragma unroll
        for (int ky = 0; ky < 3; ++ky) {
            int iy = iy0 + ky;
#pragma unroll
            for (int kx = 0; kx < 3; ++kx) {
                int ix = ix0 + kx;
                bool ok = (iy >= 0) && (iy < IH) && (ix >= 0) && (ix < IW);
                x[ky * 3 + kx] = ok ? ipc[iy * IW + ix] : 0.0f;
            }
        }
#pragma unroll
        for (int o = 0; o < OCT; ++o) {
            const float* wp = w + ((g * OCT + o) * IC + ic) * 9;
#pragma unroll
            for (int k = 0; k < 9; ++k) acc[o] = fmaf(wp[k], x[k], acc[o]);
        }
    }
#pragma unroll
    for (int o = 0; o < OCT; ++o) {
        float v = acc[o];
        if (RELU) v = fmaxf(v, 0.0f);
        out[(size_t)(b * OC + g * OCT + o) * POS + px] = v;
    }
}

// ---------------------------------------------------------------------------
// split-K 3x3 conv: SPLIT partial IC-range sums into part[].
// ---------------------------------------------------------------------------
template <int IC, int OC, int OCT, int IH, int IW, int STRIDE, int SPLIT>
__global__ __launch_bounds__(256) void convS_k(const float* __restrict__ in,
                                               const float* __restrict__ w,
                                               float* __restrict__ part) {
    constexpr int OH = (IH + 2 - 3) / STRIDE + 1;
    constexpr int OW = (IW + 2 - 3) / STRIDE + 1;
    constexpr int POS = OH * OW;
    constexpr int G = OC / OCT;
    constexpr int TOT = BATCH * G * POS;
    constexpr int ICS = IC / SPLIT;
    constexpr int N = BATCH * OC * POS;
    int idx = blockIdx.x * 256 + threadIdx.x;
    if (idx >= TOT * SPLIT) return;
    int s = idx / TOT, r = idx % TOT;
    int px = r % POS;
    int g = (r / POS) % G;
    int b = r / (POS * G);
    int ox = px % OW, oy = px / OW;
    int iy0 = oy * STRIDE - 1, ix0 = ox * STRIDE - 1;

    float acc[OCT];
#pragma unroll
    for (int o = 0; o < OCT; ++o) acc[o] = 0.0f;

    const float* ip = in + (size_t)b * IC * IH * IW;
    for (int ic = s * ICS; ic < (s + 1) * ICS; ++ic) {
        const float* ipc = ip + ic * IH * IW;
        float x[9];
#pragma unroll
        for (int ky = 0; ky < 3; ++ky) {
            int iy = iy0 + ky;
#pragma unroll
            for (int kx = 0; kx < 3; ++kx) {
                int ix = ix0 + kx;
                bool ok = (iy >= 0) && (iy < IH) && (ix >= 0) && (ix < IW);
                x[ky * 3 + kx] = ok ? ipc[iy * IW + ix] : 0.0f;
            }
        }
#pragma unroll
        for (int o = 0; o < OCT; ++o) {
            const float* wp = w + ((g * OCT + o) * IC + ic) * 9;
#pragma unroll
            for (int k = 0; k < 9; ++k) acc[o] = fmaf(wp[k], x[k], acc[o]);
        }
    }
#pragma unroll
    for (int o = 0; o < OCT; ++o)
        part[(size_t)s * N + (size_t)(b * OC + g * OCT + o) * POS + px] = acc[o];
}

// ---------------------------------------------------------------------------
// reduce split-K partials + bias + relu
// ---------------------------------------------------------------------------
template <int OC, int POS, int SPLIT, bool RELU, bool HASB>
__global__ __launch_bounds__(256) void reduce_k(const float* __restrict__ part,
                                                const float* __restrict__ bias,
                                                float* __restrict__ out) {
    constexpr int N = BATCH * OC * POS;
    int idx = blockIdx.x * 256 + threadIdx.x;
    if (idx >= N) return;
    int oc = (idx / POS) % OC;
    float a = HASB ? bias[oc] : 0.0f;
#pragma unroll
    for (int s = 0; s < SPLIT; ++s) a += part[(size_t)s * N + idx];
    out[idx] = RELU ? fmaxf(a, 0.0f) : a;
}

// ---------------------------------------------------------------------------
// fc1: folds cw1's split-16 reduce (+cb1+relu) into xin, then
// h1[b,r] = relu(fw1[r,:] . xin + fb1[r]).  512 blocks, 1 row per wave.
// ---------------------------------------------------------------------------
__global__ __launch_bounds__(256) void fc1_k(const float* __restrict__ part_cw1,
                                             const float* __restrict__ cb1,
                                             const float* __restrict__ fw1,
                                             const float* __restrict__ fb1,
                                             float* __restrict__ h1) {
    __shared__ float xin[1024];
    int t = threadIdx.x;
    int b = blockIdx.x >> 6;
    int rgrp = blockIdx.x & 63;
    int wave = t >> 6, lane = t & 63;

    for (int i = t; i < 1024; i += 256) {
        float v = cb1[i >> 4];        // xg1 flat idx i = oc*16+px, POS=16
#pragma unroll
        for (int s = 0; s < 16; ++s) v += part_cw1[s * 8192 + b * 1024 + i];
        xin[i] = fmaxf(v, 0.0f);
    }
    __syncthreads();

    int r = (rgrp << 2) | wave;       // 0..255
    const float4* w4 = (const float4*)(fw1 + r * 1024);
    const float4* x4 = (const float4*)xin;
    float acc = 0.0f;
#pragma unroll
    for (int jj = 0; jj < 4; ++jj) {
        float4 wv = w4[lane + 64 * jj];
        float4 xv = x4[lane + 64 * jj];
        acc = fmaf(wv.x, xv.x, acc);
        acc = fmaf(wv.y, xv.y, acc);
        acc = fmaf(wv.z, xv.z, acc);
        acc = fmaf(wv.w, xv.w, acc);
    }
#pragma unroll
    for (int m = 32; m; m >>= 1) acc += __shfl_xor(acc, m, 64);
    if (lane == 0) h1[b * 256 + r] = fmaxf(acc + fb1[r], 0.0f);
}

// ---------------------------------------------------------------------------
// fc2+fc3+fuse merged (keeps R8's good idea), now folding lw2's split-8
// partials (R7's fuse_k fold, proven cheap). One block per batch.
//   h2 = relu(fw2 @ h1 + fb2); xg = fw3 @ h2 + fb3
//   bg[b,d,px] = fub[d] + sum_c fuw[d,c]*relu(xg[c] + sum_s part_lw2[s,...])
// ---------------------------------------------------------------------------
__global__ __launch_bounds__(256) void fc23fuse_k(const float* __restrict__ h1,
                                                  const float* __restrict__ fw2,
                                                  const float* __restrict__ fb2,
                                                  const float* __restrict__ fw3,
                                                  const float* __restrict__ fb3,
                                                  const float* __restrict__ part_lw2,
                                                  const float* __restrict__ fuw,
                                                  const float* __restrict__ fub,
                                                  float* __restrict__ bg) {
    __shared__ float h2[128];
    __shared__ float xg[64];
    int b = blockIdx.x, t = threadIdx.x;
    int wave = t >> 6, lane = t & 63;

    float4 xv1 = ((const float4*)(h1 + b * 256))[lane];
#pragma unroll 4
    for (int i = 0; i < 32; ++i) {
        int r = wave * 32 + i;
        float4 wv = ((const float4*)(fw2 + r * 256))[lane];
        float acc = fmaf(wv.x, xv1.x, fmaf(wv.y, xv1.y, fmaf(wv.z, xv1.z, wv.w * xv1.w)));
#pragma unroll
        for (int m = 32; m; m >>= 1) acc += __shfl_xor(acc, m, 64);
        if (lane == 0) h2[r] = fmaxf(acc + fb2[r], 0.0f);
    }
    __syncthreads();

    float2 xv2 = ((const float2*)h2)[lane];
#pragma unroll 4
    for (int i = 0; i < 16; ++i) {
        int r = wave * 16 + i;
        float2 wv = ((const float2*)(fw3 + r * 128))[lane];
        float acc = fmaf(wv.x, xv2.x, wv.y * xv2.y);
#pragma unroll
        for (int m = 32; m; m >>= 1) acc += __shfl_xor(acc, m, 64);
        if (lane == 0) xg[r] = acc + fb3[r];
    }
    __syncthreads();

    int px = t;
    float acc[8];
#pragma unroll
    for (int d = 0; d < 8; ++d) acc[d] = fub[d];
    for (int c = 0; c < 64; ++c) {
        int base = (b * 64 + c) * 256 + px;
        float xlv = 0.0f;
#pragma unroll
        for (int s = 0; s < 8; ++s) xlv += part_lw2[s * 131072 + base];
        float f = fmaxf(xg[c] + xlv, 0.0f);
#pragma unroll
        for (int d = 0; d < 8; ++d) acc[d] = fmaf(fuw[d * 64 + c], f, acc[d]);
    }
#pragma unroll
    for (int d = 0; d < 8; ++d) bg[(b * 8 + d) * 256 + px] = acc[d];
}

// ---------------------------------------------------------------------------
// guide+slice (unchanged): vertical-first separable blur, sliding register
// windows, per-px guide MLP + trilinear grid slice.
// ---------------------------------------------------------------------------
__global__ __launch_bounds__(256) void guide_slice_k(const float* __restrict__ lqs,
                                                     const float* __restrict__ bgp,
                                                     const float* __restrict__ gw1,
                                                     const float* __restrict__ gb1,
                                                     const float* __restrict__ gw2,
                                                     const float* __restrict__ gb2,
                                                     float* __restrict__ out) {
    constexpr int TW = 64, TH = 32;
    __shared__ float sBH[3][TH][81];
    __shared__ float sBG[2048];
    __shared__ float sW1[48], sB1[16], sW2[16], sB2v[1];

    int t = threadIdx.x;
    int bx = blockIdx.x & 15;
    int by = (blockIdx.x >> 4) & 31;
    int b = blockIdx.x >> 9;
    int x0 = bx * TW, y0 = by * TH;

    float gv[17];
    {
        float gs = 0.0f;
#pragma unroll
        for (int i = 0; i < 17; ++i) {
            float d = (float)i - 8.0f;
            gv[i] = expf(-(d * d) * 0.125f);
            gs += gv[i];
        }
        float inv = 1.0f / gs;
#pragma unroll
        for (int i = 0; i < 17; ++i) gv[i] *= inv;
    }

    for (int i = t; i < 2048; i += 256) sBG[i] = bgp[b * 2048 + i];
    if (t < 48) sW1[t] = gw1[t];
    if (t < 16) { sB1[t] = gb1[t]; sW2[t] = gw2[t]; }
    if (t == 0) sB2v[0] = gb2[0];

    if (t < 240) {
        int c = t / 80, xo = t % 80;
        int gx = reflect1024(x0 + xo - 8);
        const float* colp = lqs + (size_t)(b * 3 + c) * HH * WW + gx;
        float win[17];
#pragma unroll
        for (int i = 0; i < 16; ++i)
            win[i] = colp[(size_t)reflect1024(y0 - 8 + i) * WW];
#pragma unroll
        for (int j = 0; j < TH; ++j) {
            win[(16 + j) % 17] = colp[(size_t)reflect1024(y0 + 8 + j) * WW];
            float acc = 0.0f;
#pragma unroll
            for (int i = 0; i < 17; ++i) acc = fmaf(gv[i], win[(j + i) % 17], acc);
            sBH[c][j][xo] = acc;
        }
    }
    __syncthreads();

    int yy = t >> 3, xs = (t & 7) * 8;
    int Y = y0 + yy;
    float fy = fminf(fmaxf((Y + 0.5f) * (1.0f / 64.0f) + 3.5f, 0.0f), 15.0f);
    float yf = floorf(fy);
    int yi = (int)yf;
    float ay = fy - yf;
    int yi1 = min(yi + 1, 15);

    float bcv[3][8];
#pragma unroll
    for (int c = 0; c < 3; ++c) {
        float win[17];
#pragma unroll
        for (int i = 0; i < 16; ++i) win[i] = sBH[c][yy][xs + i];
#pragma unroll
        for (int j = 0; j < 8; ++j) {
            win[(16 + j) % 17] = sBH[c][yy][xs + 16 + j];
            float acc = 0.0f;
#pragma unroll
            for (int i = 0; i < 17; ++i) acc = fmaf(gv[i], win[(j + i) % 17], acc);
            bcv[c][j] = acc;
        }
    }

    float val[8];
#pragma unroll
    for (int j = 0; j < 8; ++j) {
        float b0 = bcv[0][j], b1 = bcv[1][j], b2 = bcv[2][j];
        float s = sB2v[0];
#pragma unroll
        for (int c = 0; c < 16; ++c) {
            float g1 = fmaf(sW1[c * 3 + 0], b0,
                       fmaf(sW1[c * 3 + 1], b1,
                       fmaf(sW1[c * 3 + 2], b2, sB1[c])));
            s = fmaf(sW2[c], fmaxf(g1, 0.0f), s);
        }
        float sig = 1.0f / (1.0f + expf(-s));
        float guide = sig * 2.0f - 0.5f;

        int X = x0 + xs + j;
        float fx = fminf(fmaxf((X + 0.5f) * (1.0f / 64.0f) + 3.5f, 0.0f), 15.0f);
        float fz = fminf(fmaxf(fmaf(guide, 4.0f, 3.5f), 0.0f), 7.0f);
        float xf = floorf(fx), zf = floorf(fz);
        int xi = (int)xf, zi = (int)zf;
        float ax = fx - xf, az = fz - zf;
        int xi1 = min(xi + 1, 15), zi1 = min(zi + 1, 7);

        const float* g0 = sBG + zi * 256;
        const float* g1p = sBG + zi1 * 256;
        int i00 = yi * 16 + xi, i01 = yi * 16 + xi1;
        int i10 = yi1 * 16 + xi, i11 = yi1 * 16 + xi1;
        float c00 = g0[i00] + az * (g1p[i00] - g0[i00]);
        float c01 = g0[i01] + az * (g1p[i01] - g0[i01]);
        float c10 = g0[i10] + az * (g1p[i10] - g0[i10]);
        float c11 = g0[i11] + az * (g1p[i11] - g0[i11]);
        float c0 = c00 + ay * (c10 - c00);
        float c1 = c01 + ay * (c11 - c01);
        val[j] = c0 + ax * (c1 - c0);
    }
    float4* op = (float4*)(out + (size_t)b * HH * WW + (size_t)Y * WW + x0 + xs);
    op[0] = make_float4(val[0], val[1], val[2], val[3]);
    op[1] = make_float4(val[4], val[5], val[6], val[7]);
}

// ---------------------------------------------------------------------------
extern "C" void kernel_launch(void* const* d_in, const int* in_sizes, int n_in,
                              void* d_out, int out_size, void* d_ws, size_t ws_size,
                              hipStream_t stream) {
    const float* lqs = (const float*)d_in[0];
    const float* evs = (const float*)d_in[1];
    const float* gw1 = (const float*)d_in[2];
    const float* gb1 = (const float*)d_in[3];
    const float* gw2 = (const float*)d_in[4];
    const float* gb2 = (const float*)d_in[5];
    const float* sw0 = (const float*)d_in[6];
    const float* sb0 = (const float*)d_in[7];
    const float* sw1 = (const float*)d_in[8];
    const float* sb1 = (const float*)d_in[9];
    const float* sw2 = (const float*)d_in[10];
    const float* sb2 = (const float*)d_in[11];
    const float* sw3 = (const float*)d_in[12];
    const float* sb3 = (const float*)d_in[13];
    const float* cw0 = (const float*)d_in[14];
    const float* cb0 = (const float*)d_in[15];
    const float* cw1 = (const float*)d_in[16];
    const float* cb1 = (const float*)d_in[17];
    const float* fw1 = (const float*)d_in[18];
    const float* fb1 = (const float*)d_in[19];
    const float* fw2 = (const float*)d_in[20];
    const float* fb2 = (const float*)d_in[21];
    const float* fw3 = (const float*)d_in[22];
    const float* fb3 = (const float*)d_in[23];
    const float* lw1 = (const float*)d_in[24];
    const float* lb1 = (const float*)d_in[25];
    const float* lw2 = (const float*)d_in[26];
    const float* fuw = (const float*)d_in[27];
    const float* fub = (const float*)d_in[28];
    float* out = (float*)d_out;

    float* ws = (float*)d_ws;
    float* o0 = ws;                  // [8,8,128,128]   1048576
    float* o1 = o0 + 1048576;        // [8,16,64,64]     524288
    float* o2 = o1 + 524288;         // [8,32,32,32]     262144
    float* o3 = o2 + 262144;         // [8,64,16,16]     131072
    float* xl1 = o3 + 131072;        // [8,64,16,16]     131072
    float* xg0 = xl1 + 131072;       // [8,64,8,8]        32768
    float* h1 = xg0 + 32768;         // [8,256]            2048
    float* bg = h1 + 2048;           // [8,8,16,16]       16384
    float* partA = bg + 16384;       // reused partials  1048576
    float* part_lw2 = partA + 1048576;   // persists     1048576
    float* part_cw1 = part_lw2 + 1048576; // persists     131072
    // total ~4.37M floats = 17.5 MB

    // lowres stream — R7's verified split-K/OCT=8 structure
    conv0_k<<<128, 256, 0, stream>>>(lqs, evs, sw0, sb0, o0);
    convN_k<8, 16, 8, 128, 128, 2, true, true><<<256, 256, 0, stream>>>(o0, sw1, sb1, o1);
    convS_k<16, 32, 8, 64, 64, 2, 4><<<512, 256, 0, stream>>>(o1, sw2, partA);
    reduce_k<32, 1024, 4, true, true><<<1024, 256, 0, stream>>>(partA, sb2, o2);
    convS_k<32, 64, 8, 32, 32, 2, 8><<<512, 256, 0, stream>>>(o2, sw3, partA);
    reduce_k<64, 256, 8, true, true><<<512, 256, 0, stream>>>(partA, sb3, o3);
    // local path
    convS_k<64, 64, 8, 16, 16, 1, 8><<<512, 256, 0, stream>>>(o3, lw1, partA);
    reduce_k<64, 256, 8, true, true><<<512, 256, 0, stream>>>(partA, lb1, xl1);
    convS_k<64, 64, 8, 16, 16, 1, 8><<<512, 256, 0, stream>>>(xl1, lw2, part_lw2);
    // (lw2 reduce folded into fc23fuse_k)
    // global path
    convS_k<64, 64, 8, 16, 16, 2, 16><<<256, 256, 0, stream>>>(o3, cw0, partA);
    reduce_k<64, 64, 16, true, true><<<128, 256, 0, stream>>>(partA, cb0, xg0);
    convS_k<64, 64, 4, 8, 8, 2, 16><<<128, 256, 0, stream>>>(xg0, cw1, part_cw1);
    // (cw1 reduce folded into fc1_k)
    fc1_k<<<512, 256, 0, stream>>>(part_cw1, cb1, fw1, fb1, h1);
    fc23fuse_k<<<8, 256, 0, stream>>>(h1, fw2, fb2, fw3, fb3, part_lw2, fuw, fub, bg);
    // highres guide + slice
    guide_slice_k<<<BATCH * 32 * 16, 256, 0, stream>>>(lqs, bg, gw1, gb1, gw2, gb2, out);
}